// Round 1
// baseline (72877.423 us; speedup 1.0000x reference)
//
#include <hip/hip_runtime.h>
#include <math.h>

#define NBLK 128
#define TPB  512
#define NW   8          // waves per block
#define Vc   50257
#define NEG_INF (-__builtin_inff())

// ---------------- wave-level helpers (wave64, no LDS, no barriers) ----------------

__device__ __forceinline__ float wsum64(float v) {
#pragma unroll
  for (int m = 32; m >= 1; m >>= 1) v += __shfl_xor(v, m, 64);
  return v;
}

__device__ __forceinline__ float red8(float v) {  // sum within 8-lane groups (per head)
  v += __shfl_xor(v, 1, 64);
  v += __shfl_xor(v, 2, 64);
  v += __shfl_xor(v, 4, 64);
  return v;
}

// out[lane] = sum_e x[e] * W[e*64+lane] + bias[lane]; x distributed one value per lane
__device__ __forceinline__ float proj64(float xv, const float* __restrict__ W,
                                        const float* __restrict__ bias, int lane) {
  float acc = 0.f;
#pragma unroll
  for (int e = 0; e < 64; ++e)
    acc = fmaf(__shfl(xv, e, 64), W[e * 64 + lane], acc);
  return acc + bias[lane];
}

__device__ __forceinline__ float ln64(float xv, const float* __restrict__ g,
                                      const float* __restrict__ b, int lane) {
  float mean = wsum64(xv) * 0.015625f;
  float d = xv - mean;
  float var = wsum64(d * d) * 0.015625f;
  float r = 1.0f / sqrtf(var + 1e-5f);
  return d * r * g[lane] + b[lane];
}

// one-shot global barrier slot (zeroed by hipMemsetAsync each launch)
__device__ __forceinline__ void gbar(int* slot) {
  __syncthreads();
  if (threadIdx.x == 0) {
    __hip_atomic_fetch_add(slot, 1, __ATOMIC_RELEASE, __HIP_MEMORY_SCOPE_AGENT);
    while (__hip_atomic_load(slot, __ATOMIC_ACQUIRE, __HIP_MEMORY_SCOPE_AGENT) < NBLK) {
      __builtin_amdgcn_s_sleep(2);
    }
  }
  __syncthreads();
}

struct LayerP {
  const float *saW3, *sab3, *caW0, *cab0, *caW3, *cab3, *cs1, *cs2, *cab1, *cab2,
              *ffW1, *ffb1, *ffW2, *ffb2, *g0, *be0, *g1, *be1, *g2, *be2;
};

// One wave processes one (b,p) row: self-attn (keys 0..t-1) -> LN1 -> rank-1
// cross-attn -> LN2 -> FF -> LN3. Returns LN3 output (per-lane feature).
__device__ float transformer_row(int lane, int t, float x, float q,
                                 const float* __restrict__ Kb, const float* __restrict__ Vb,
                                 const float* __restrict__ wvb, const LayerP& P) {
  const float SQ8 = sqrtf(8.0f);
  // ---- self attention, two-pass softmax; lane = (h*8+d) ----
  float mh = NEG_INF;
  for (int k = 0; k < t; ++k) {
    float s = red8(q * Kb[k * 64 + lane]) / SQ8;
    mh = fmaxf(mh, s);
  }
  float l = 0.f, o = 0.f;
  for (int k = 0; k < t; ++k) {
    float s = red8(q * Kb[k * 64 + lane]) / SQ8;
    float pw = expf(s - mh);
    l += pw;
    o = fmaf(pw, Vb[k * 64 + lane], o);
  }
  float attn = o / l;
  float y1 = ln64(x + proj64(attn, P.saW3, P.sab3, lane), P.g0, P.be0, lane);
  // ---- cross attention: K,V are rank-1 in wv ----
  float qc = proj64(y1, P.caW0, P.cab0, lane);
  float pa = red8(qc * P.cs1[lane]);   // per-head scalar A (replicated in 8-lane group)
  float pc = red8(qc * P.cab1[lane]);  // per-head scalar C
  float mc = NEG_INF;
  for (int k = 0; k < t; ++k) {
    float s = (pa * wvb[k] + pc) / SQ8;
    mc = fmaxf(mc, s);
  }
  float lc = 0.f, z = 0.f;
  for (int k = 0; k < t; ++k) {
    float s = (pa * wvb[k] + pc) / SQ8;
    float pw = expf(s - mc);
    lc += pw;
    z = fmaf(pw, wvb[k], z);
  }
  float oc = fmaf(z / lc, P.cs2[lane], P.cab2[lane]);
  float y2 = ln64(y1 + proj64(oc, P.caW3, P.cab3, lane), P.g1, P.be1, lane);
  // ---- FF ----
  float f = fmaxf(proj64(y2, P.ffW1, P.ffb1, lane), 0.f);
  float y3 = ln64(y2 + proj64(f, P.ffW2, P.ffb2, lane), P.g2, P.be2, lane);
  return y3;
}

__global__ __launch_bounds__(TPB) void gen_kernel(
    const float* __restrict__ noise, const float* __restrict__ lin_W,
    const float* __restrict__ lin_b, const float* __restrict__ sa_W,
    const float* __restrict__ sa_b, const float* __restrict__ ca_W,
    const float* __restrict__ ca_b, const float* __restrict__ ff_W1,
    const float* __restrict__ ff_b1, const float* __restrict__ ff_W2,
    const float* __restrict__ ff_b2, const float* __restrict__ ln_g,
    const float* __restrict__ ln_b, const float* __restrict__ emb,
    const float* __restrict__ soft_W, const float* __restrict__ soft_b,
    const int* __restrict__ start_id, float* __restrict__ dout,
    float* __restrict__ wsf) {
  const int tid = threadIdx.x, lane = tid & 63, wvid = tid >> 6;
  const int blk = blockIdx.x;
  const int gwave = blk * NW + wvid;        // 0..1023
  const int gtid = blk * TPB + tid;         // 0..65535

  // ---- workspace layout ----
  int* bars = (int*)wsf;                    // 512 one-shot barrier slots
  float* pe = wsf + 512;                    // (64,64)
  float* wva = pe + 4096;                   // (8,64)  w_lin
  float* cs1 = wva + 512;                   // (2,64) colsums of ca_W[n][1]
  float* cs2 = cs1 + 128;                   // (2,64) colsums of ca_W[n][2]
  float* tmpb = cs2 + 128;                  // (8,64)
  float* Y   = tmpb + 512;                  // (8,64,64)
  float* Q1  = Y + 32768;
  float* K1  = Q1 + 32768;
  float* V1  = K1 + 32768;
  float* K2  = V1 + 32768;
  float* V2  = K2 + 32768;
  float* L1o = V2 + 32768;
  float* tokf = L1o + 32768;                // (8,64)
  float* logits = tokf + 512;               // (8,V)
  float* stat_m = logits + 8 * Vc;          // (8,128)
  float* stat_s = stat_m + 1024;            // (8,128)
  int*   stat_i = (int*)(stat_s + 1024);    // (8,128)
  float* bmv = (float*)(stat_i + 1024);     // (8)
  float* bSv = bmv + 8;                     // (8)

  __shared__ float sm[NW][8];
  __shared__ int   si[NW][8];
  __shared__ float ssm[NW][8];
  __shared__ float bmx[8];
  __shared__ int   bix[8];
  __shared__ float ftile[512];

  int barid = 0;

  LayerP LP[2];
#pragma unroll
  for (int n = 0; n < 2; ++n) {
    LP[n].saW3 = sa_W + (n * 4 + 3) * 4096; LP[n].sab3 = sa_b + (n * 4 + 3) * 64;
    LP[n].caW0 = ca_W + (n * 4 + 0) * 4096; LP[n].cab0 = ca_b + (n * 4 + 0) * 64;
    LP[n].caW3 = ca_W + (n * 4 + 3) * 4096; LP[n].cab3 = ca_b + (n * 4 + 3) * 64;
    LP[n].cs1 = cs1 + n * 64;               LP[n].cs2 = cs2 + n * 64;
    LP[n].cab1 = ca_b + (n * 4 + 1) * 64;   LP[n].cab2 = ca_b + (n * 4 + 2) * 64;
    LP[n].ffW1 = ff_W1 + n * 4096;          LP[n].ffb1 = ff_b1 + n * 64;
    LP[n].ffW2 = ff_W2 + n * 4096;          LP[n].ffb2 = ff_b2 + n * 64;
    LP[n].g0 = ln_g + (n * 3 + 0) * 64;     LP[n].be0 = ln_b + (n * 3 + 0) * 64;
    LP[n].g1 = ln_g + (n * 3 + 1) * 64;     LP[n].be1 = ln_b + (n * 3 + 1) * 64;
    LP[n].g2 = ln_g + (n * 3 + 2) * 64;     LP[n].be2 = ln_b + (n * 3 + 2) * 64;
  }

  // ================= init I1: pos-enc (fp64) + first linear =================
  for (int i = gtid; i < 4096; i += NBLK * TPB) {
    int s = i >> 6, e = i & 63;
    double ang = (double)s / pow(10000.0, (double)(e & ~1) / 64.0);
    pe[i] = (float)((e & 1) ? cos(ang) : sin(ang));
  }
  if ((gwave & 127) == 0) {
    int b = gwave >> 7;
    tmpb[b * 64 + lane] = proj64(noise[b * 64 + lane], lin_W, lin_b, lane);
  }
  gbar(&bars[barid++]);
  // ===== init I2: second linear -> wv; Y0 row + its QKV; cross colsums =====
  if ((gwave & 127) == 0) {
    int b = gwave >> 7;
    wva[b * 64 + lane] = proj64(tmpb[b * 64 + lane], lin_W + 4096, lin_b + 64, lane);
    float y0 = emb[start_id[0] * 64 + lane] + pe[lane];
    Y[(b * 64) * 64 + lane] = y0;
    Q1[(b * 64) * 64 + lane] = proj64(y0, sa_W, sa_b, lane);
    K1[(b * 64) * 64 + lane] = proj64(y0, sa_W + 4096, sa_b + 64, lane);
    V1[(b * 64) * 64 + lane] = proj64(y0, sa_W + 2 * 4096, sa_b + 128, lane);
  }
  if ((gwave & 127) == 8 && gwave < 512) {  // 4 waves: colsum vectors
    int id = gwave >> 7; int n = id >> 1, wh = id & 1;
    const float* Wp = ca_W + (n * 4 + 1 + wh) * 4096;
    float s = 0.f;
    for (int e = 0; e < 64; ++e) s += Wp[e * 64 + lane];
    (wh ? cs2 : cs1)[n * 64 + lane] = s;
  }
  gbar(&bars[barid++]);

  // ========================= autoregressive steps =========================
  for (int t = 1; t <= 63; ++t) {
    // ---- P1: write prev-step probs; layer-1 rows 0..t-1 (+ layer-2 K/V) ----
    if (t > 1) {
      int base = (t - 2) * Vc;
      for (int i = gtid; i < 8 * Vc; i += NBLK * TPB) {
        int b = i / Vc, v = i - b * Vc;
        dout[b * 63 * Vc + base + v] = expf(logits[i] - bmv[b]) / bSv[b];
      }
    }
    {
      int nrows = 8 * t;
      if (gwave < nrows) {
        int b = gwave & 7, p = gwave >> 3;
        float x = Y[(b * 64 + p) * 64 + lane];
        float q = Q1[(b * 64 + p) * 64 + lane];
        float out = transformer_row(lane, t, x, q, K1 + b * 4096, V1 + b * 4096,
                                    wva + b * 64, LP[0]);
        L1o[(b * 64 + p) * 64 + lane] = out;
        K2[(b * 64 + p) * 64 + lane] = proj64(out, sa_W + 5 * 4096, sa_b + 5 * 64, lane);
        V2[(b * 64 + p) * 64 + lane] = proj64(out, sa_W + 6 * 4096, sa_b + 6 * 64, lane);
      }
    }
    gbar(&bars[barid++]);
    // ---- P2: layer-2, query row t-1 only -> tok_feat ----
    if ((gwave & 127) == 0) {
      int b = gwave >> 7, p = t - 1;
      float x = L1o[(b * 64 + p) * 64 + lane];
      float q = proj64(x, sa_W + 4 * 4096, sa_b + 4 * 64, lane);
      tokf[b * 64 + lane] = transformer_row(lane, t, x, q, K2 + b * 4096,
                                            V2 + b * 4096, wva + b * 64, LP[1]);
    }
    gbar(&bars[barid++]);
    // ---- P3: logits over V + per-block softmax/argmax stats ----
    {
      if (tid < 512) ftile[tid] = tokf[tid];
      __syncthreads();
      int v = gtid;
      bool valid = v < Vc;
      float lg[8];
      if (valid) {
        float sb = soft_b[v];
#pragma unroll
        for (int b = 0; b < 8; ++b) lg[b] = sb;
        for (int e = 0; e < 64; ++e) {
          float wc = soft_W[e * Vc + v];
#pragma unroll
          for (int b = 0; b < 8; ++b) lg[b] = fmaf(ftile[b * 64 + e], wc, lg[b]);
        }
#pragma unroll
        for (int b = 0; b < 8; ++b) logits[b * Vc + v] = lg[b];
      } else {
#pragma unroll
        for (int b = 0; b < 8; ++b) lg[b] = NEG_INF;
      }
#pragma unroll
      for (int b = 0; b < 8; ++b) {
        float m = lg[b]; int ix = valid ? v : 0x7fffffff;
#pragma unroll
        for (int msk = 1; msk < 64; msk <<= 1) {
          float om = __shfl_xor(m, msk, 64);
          int oi = __shfl_xor(ix, msk, 64);
          if (om > m || (om == m && oi < ix)) { m = om; ix = oi; }
        }
        if (lane == 0) { sm[wvid][b] = m; si[wvid][b] = ix; }
      }
      __syncthreads();
      if (tid < 8) {
        int b = tid; float m = NEG_INF; int ix = 0x7fffffff;
        for (int w = 0; w < NW; ++w) {
          float om = sm[w][b]; int oi = si[w][b];
          if (om > m || (om == m && oi < ix)) { m = om; ix = oi; }
        }
        bmx[b] = m; bix[b] = ix;
      }
      __syncthreads();
#pragma unroll
      for (int b = 0; b < 8; ++b) {
        float c = (lg[b] == NEG_INF) ? 0.f : expf(lg[b] - bmx[b]);
        float s = wsum64(c);
        if (lane == 0) ssm[wvid][b] = s;
      }
      __syncthreads();
      if (tid < 8) {
        int b = tid; float s = 0.f;
        for (int w = 0; w < NW; ++w) s += ssm[w][b];
        stat_m[b * NBLK + blk] = bmx[b];
        stat_i[b * NBLK + blk] = bix[b];
        stat_s[b * NBLK + blk] = s;
      }
    }
    gbar(&bars[barid++]);
    // ---- P4: per-batch reduce; argmax -> embed -> new row QKV ----
    if ((gwave & 127) == 0) {
      int b = gwave >> 7;
      float m0 = stat_m[b * NBLK + lane], s0 = stat_s[b * NBLK + lane];
      int   i0 = stat_i[b * NBLK + lane];
      float m1 = stat_m[b * NBLK + 64 + lane], s1 = stat_s[b * NBLK + 64 + lane];
      int   i1 = stat_i[b * NBLK + 64 + lane];
      float m = m0; int ix = i0;
      if (m1 > m || (m1 == m && i1 < ix)) { m = m1; ix = i1; }
#pragma unroll
      for (int msk = 1; msk < 64; msk <<= 1) {
        float om = __shfl_xor(m, msk, 64);
        int oi = __shfl_xor(ix, msk, 64);
        if (om > m || (om == m && oi < ix)) { m = om; ix = oi; }
      }
      float z = 0.f;
      if (m0 != NEG_INF) z += s0 * expf(m0 - m);
      if (m1 != NEG_INF) z += s1 * expf(m1 - m);
      float S = wsum64(z);
      if (lane == 0) { bmv[b] = m; bSv[b] = S; }
      if (t < 63) {
        float y = emb[ix * 64 + lane] + pe[t * 64 + lane];
        Y[(b * 64 + t) * 64 + lane] = y;
        Q1[(b * 64 + t) * 64 + lane] = proj64(y, sa_W, sa_b, lane);
        K1[(b * 64 + t) * 64 + lane] = proj64(y, sa_W + 4096, sa_b + 64, lane);
        V1[(b * 64 + t) * 64 + lane] = proj64(y, sa_W + 2 * 4096, sa_b + 128, lane);
      }
    }
    gbar(&bars[barid++]);
  }
  // ---- final probs write for t = 63 ----
  for (int i = gtid; i < 8 * Vc; i += NBLK * TPB) {
    int b = i / Vc, v = i - b * Vc;
    dout[b * 63 * Vc + 62 * Vc + v] = expf(logits[i] - bmv[b]) / bSv[b];
  }
}

extern "C" void kernel_launch(void* const* d_in, const int* in_sizes, int n_in,
                              void* d_out, int out_size, void* d_ws, size_t ws_size,
                              hipStream_t stream) {
  (void)in_sizes; (void)n_in; (void)out_size; (void)ws_size;
  // zero the one-shot barrier slots (graph-capturable)
  hipMemsetAsync(d_ws, 0, 512 * sizeof(int), stream);
  gen_kernel<<<dim3(NBLK), dim3(TPB), 0, stream>>>(
      (const float*)d_in[0], (const float*)d_in[1], (const float*)d_in[2],
      (const float*)d_in[3], (const float*)d_in[4], (const float*)d_in[5],
      (const float*)d_in[6], (const float*)d_in[7], (const float*)d_in[8],
      (const float*)d_in[9], (const float*)d_in[10], (const float*)d_in[11],
      (const float*)d_in[12], (const float*)d_in[13], (const float*)d_in[14],
      (const float*)d_in[15], (const int*)d_in[16],
      (float*)d_out, (float*)d_ws);
}

// Round 2
// 39081.839 us; speedup vs baseline: 1.8647x; 1.8647x over previous
//
#include <hip/hip_runtime.h>
#include <math.h>

#define Vc 50257
#define NEG_INF (-__builtin_inff())
#define CHUNK 898   // vocab columns per wide block (56*898 = 50288 >= 50257)
#define NP3 56      // wide (vocab) blocks
#define NTB 8       // transformer blocks (one per batch)

// ---------------- wave-level helpers (wave64, no LDS, no barriers) ----------------

__device__ __forceinline__ float wsum64(float v) {
#pragma unroll
  for (int m = 32; m >= 1; m >>= 1) v += __shfl_xor(v, m, 64);
  return v;
}

__device__ __forceinline__ float red8(float v) {  // sum within 8-lane groups (per head)
  v += __shfl_xor(v, 1, 64);
  v += __shfl_xor(v, 2, 64);
  v += __shfl_xor(v, 4, 64);
  return v;
}

// out[lane] = sum_e x[e] * W[e*64+lane] + bias[lane]; x distributed one value per lane
__device__ __forceinline__ float proj64(float xv, const float* __restrict__ W,
                                        const float* __restrict__ bias, int lane) {
  float acc = 0.f;
#pragma unroll
  for (int e = 0; e < 64; ++e)
    acc = fmaf(__shfl(xv, e, 64), W[e * 64 + lane], acc);
  return acc + bias[lane];
}

__device__ __forceinline__ float ln64(float xv, const float* __restrict__ g,
                                      const float* __restrict__ b, int lane) {
  float mean = wsum64(xv) * 0.015625f;
  float d = xv - mean;
  float var = wsum64(d * d) * 0.015625f;
  float r = 1.0f / sqrtf(var + 1e-5f);
  return d * r * g[lane] + b[lane];
}

// ------------- coherent (cross-XCD) access: relaxed atomics, NO cache wipes -------------

__device__ __forceinline__ float cloadf(const float* p) {
  return __hip_atomic_load(p, __ATOMIC_RELAXED, __HIP_MEMORY_SCOPE_AGENT);
}
__device__ __forceinline__ int cloadi(const int* p) {
  return __hip_atomic_load(p, __ATOMIC_RELAXED, __HIP_MEMORY_SCOPE_AGENT);
}
__device__ __forceinline__ void cstoref(float* p, float v) {
  __hip_atomic_store(p, v, __ATOMIC_RELAXED, __HIP_MEMORY_SCOPE_AGENT);
}
__device__ __forceinline__ void cstorei(int* p, int v) {
  __hip_atomic_store(p, v, __ATOMIC_RELAXED, __HIP_MEMORY_SCOPE_AGENT);
}
// spin until *f >= target (relaxed polls: no buffer_inv). waitcnt drains before return.
__device__ __forceinline__ void spin_until(int* f, int target) {
  while (__hip_atomic_load(f, __ATOMIC_RELAXED, __HIP_MEMORY_SCOPE_AGENT) < target)
    __builtin_amdgcn_s_sleep(8);
  __builtin_amdgcn_s_waitcnt(0);
}
// drain this wave's (coherent) stores to the coherence point, then bump flag.
__device__ __forceinline__ void postflag(int* f, int lane) {
  __builtin_amdgcn_s_waitcnt(0);
  if (lane == 0) __hip_atomic_fetch_add(f, 1, __ATOMIC_RELAXED, __HIP_MEMORY_SCOPE_AGENT);
}

struct LayerR {
  const float *saW3, *sab3, *caW0, *cab0, *caW3, *cab3,
              *ffW1, *ffb1, *ffW2, *ffb2, *g0, *be0, *g1, *be1, *g2, *be2;
  float cs1_r, cs2_r, cab1_r, cab2_r;  // per-lane register values
};

// One wave, one row: self-attn (keys 0..t-1, K/V in LDS) -> LN -> rank-1
// cross-attn (wv broadcast from register) -> LN -> FF -> LN.
__device__ __forceinline__ float transformer_row(int lane, int t, float x, float q,
                                                 const float* Kb, const float* Vb,
                                                 float wv_r, const LayerR& P) {
  const float SQ8 = sqrtf(8.0f);
  float mh = NEG_INF;
  for (int k = 0; k < t; ++k) {
    float s = red8(q * Kb[k * 64 + lane]) / SQ8;
    mh = fmaxf(mh, s);
  }
  float l = 0.f, o = 0.f;
  for (int k = 0; k < t; ++k) {
    float s = red8(q * Kb[k * 64 + lane]) / SQ8;
    float pw = expf(s - mh);
    l += pw;
    o = fmaf(pw, Vb[k * 64 + lane], o);
  }
  float attn = o / l;
  float y1 = ln64(x + proj64(attn, P.saW3, P.sab3, lane), P.g0, P.be0, lane);
  float qc = proj64(y1, P.caW0, P.cab0, lane);
  float pa = red8(qc * P.cs1_r);
  float pc = red8(qc * P.cab1_r);
  float mc = NEG_INF;
  for (int k = 0; k < t; ++k) {
    float wk = __shfl(wv_r, k, 64);
    float s = (pa * wk + pc) / SQ8;
    mc = fmaxf(mc, s);
  }
  float lc = 0.f, z = 0.f;
  for (int k = 0; k < t; ++k) {
    float wk = __shfl(wv_r, k, 64);
    float s = (pa * wk + pc) / SQ8;
    float pw = expf(s - mc);
    lc += pw;
    z = fmaf(pw, wk, z);
  }
  float oc = fmaf(z / lc, P.cs2_r, P.cab2_r);
  float y2 = ln64(y1 + proj64(oc, P.caW3, P.cab3, lane), P.g1, P.be1, lane);
  float f = fmaxf(proj64(y2, P.ffW1, P.ffb1, lane), 0.f);
  float y3 = ln64(y2 + proj64(f, P.ffW2, P.ffb2, lane), P.g2, P.be2, lane);
  return y3;
}

__global__ __launch_bounds__(1024) void gen_kernel(
    const float* __restrict__ noise, const float* __restrict__ lin_W,
    const float* __restrict__ lin_b, const float* __restrict__ sa_W,
    const float* __restrict__ sa_b, const float* __restrict__ ca_W,
    const float* __restrict__ ca_b, const float* __restrict__ ff_W1,
    const float* __restrict__ ff_b1, const float* __restrict__ ff_W2,
    const float* __restrict__ ff_b2, const float* __restrict__ ln_g,
    const float* __restrict__ ln_b, const float* __restrict__ emb,
    const float* __restrict__ soft_W, const float* __restrict__ soft_b,
    const int* __restrict__ start_id, float* __restrict__ dout,
    float* __restrict__ wsf) {
  const int tid = threadIdx.x, lane = tid & 63, wvid = tid >> 6;
  const int bid = blockIdx.x;

  // 64768 B static LDS; transformer blocks and vocab blocks alias it differently.
  __shared__ float lds[16192];

  // ---- workspace layout (all cross-block regions accessed coherently) ----
  int* F  = (int*)wsf;          // [64] tok_feat-ready counts (target 8)
  int* C3 = (int*)wsf + 64;     // [64] stats-ready counts   (target 56)
  int* R  = (int*)wsf + 128;    // [64] m/S-ready counts     (target 8)
  float* tokf_g  = wsf + 1024;  // (8,64)
  float* stats_m = wsf + 1536;  // (8,64) use 56
  float* stats_s = wsf + 2048;
  int*   stats_i = (int*)(wsf + 2560);
  float* mS_g    = wsf + 3072;  // (8,2)
  float* Yg_all  = wsf + 4096;        // (8,63,64) block-local (normal access)
  float* Qg_all  = Yg_all + 8 * 4032; // (8,63,64)
  float* pe_all  = Qg_all + 8 * 4032; // (8,63,64)

  if (bid < NTB) {
    // =================== transformer block: one batch, all in LDS ===================
    const int b = bid;
    float* K1 = lds;             // (63,64)
    float* V1 = lds + 4032;
    float* K2 = lds + 8064;
    float* V2 = lds + 12096;
    float* x2row = lds + 16128;  // (64)
    float* Yg = Yg_all + b * 4032;
    float* Qg = Qg_all + b * 4032;
    float* peg = pe_all + b * 4032;

    // ---- init (all waves redundantly compute per-lane constants) ----
    float nz = noise[b * 64 + lane];
    float t1v = proj64(nz, lin_W, lin_b, lane);
    float wv_r = proj64(t1v, lin_W + 4096, lin_b + 64, lane);

    LayerR L[2];
#pragma unroll
    for (int n = 0; n < 2; ++n) {
      L[n].saW3 = sa_W + (n * 4 + 3) * 4096; L[n].sab3 = sa_b + (n * 4 + 3) * 64;
      L[n].caW0 = ca_W + (n * 4 + 0) * 4096; L[n].cab0 = ca_b + (n * 4 + 0) * 64;
      L[n].caW3 = ca_W + (n * 4 + 3) * 4096; L[n].cab3 = ca_b + (n * 4 + 3) * 64;
      L[n].ffW1 = ff_W1 + n * 4096;          L[n].ffb1 = ff_b1 + n * 64;
      L[n].ffW2 = ff_W2 + n * 4096;          L[n].ffb2 = ff_b2 + n * 64;
      L[n].g0 = ln_g + (n * 3 + 0) * 64;     L[n].be0 = ln_b + (n * 3 + 0) * 64;
      L[n].g1 = ln_g + (n * 3 + 1) * 64;     L[n].be1 = ln_b + (n * 3 + 1) * 64;
      L[n].g2 = ln_g + (n * 3 + 2) * 64;     L[n].be2 = ln_b + (n * 3 + 2) * 64;
      L[n].cab1_r = ca_b[(n * 4 + 1) * 64 + lane];
      L[n].cab2_r = ca_b[(n * 4 + 2) * 64 + lane];
      float c1 = 0.f, c2 = 0.f;
      for (int e = 0; e < 64; ++e) {
        c1 += ca_W[(n * 4 + 1) * 4096 + e * 64 + lane];
        c2 += ca_W[(n * 4 + 2) * 4096 + e * 64 + lane];
      }
      L[n].cs1_r = c1; L[n].cs2_r = c2;
    }

    // pe rows (fp64, once) into block-local global scratch
    for (int r = wvid; r < 63; r += 16) {
      double ang = (double)r / pow(10000.0, (double)(lane & 62) / 64.0);
      peg[r * 64 + lane] = (float)((lane & 1) ? cos(ang) : sin(ang));
    }
    if (wvid == 0) {
      float y0 = emb[start_id[0] * 64 + lane] + ((lane & 1) ? 1.0f : 0.0f);
      Yg[lane] = y0;
      Qg[lane] = proj64(y0, sa_W, sa_b, lane);
      K1[lane] = proj64(y0, sa_W + 4096, sa_b + 64, lane);
      V1[lane] = proj64(y0, sa_W + 2 * 4096, sa_b + 128, lane);
    }

    for (int t = 1; t <= 63; ++t) {
      __syncthreads();  // K1/V1 row t-1 (wave 0) visible; K2/V2 free to overwrite
      // ---- P1: layer-1 for rows 0..t-1; produce layer-2 K/V ----
      for (int p = wvid; p < t; p += 16) {
        float x = Yg[p * 64 + lane];
        float q = Qg[p * 64 + lane];
        float out = transformer_row(lane, t, x, q, K1, V1, wv_r, L[0]);
        K2[p * 64 + lane] = proj64(out, sa_W + 5 * 4096, sa_b + 5 * 64, lane);
        V2[p * 64 + lane] = proj64(out, sa_W + 6 * 4096, sa_b + 6 * 64, lane);
        if (p == t - 1) x2row[lane] = out;
      }
      __syncthreads();  // K2/V2, x2row visible to wave 0
      if (wvid == 0) {
        // ---- P2: layer-2 for row t-1 -> tok_feat ----
        float x2 = x2row[lane];
        float q2 = proj64(x2, sa_W + 4 * 4096, sa_b + 4 * 64, lane);
        float tf = transformer_row(lane, t, x2, q2, K2, V2, wv_r, L[1]);
        cstoref(&tokf_g[b * 64 + lane], tf);
        postflag(&F[t], lane);
        // ---- wait vocab stats; reduce; publish m,S; next row ----
        spin_until(&C3[t], NP3);
        bool act = lane < NP3;
        float m  = act ? cloadf(&stats_m[b * 64 + lane]) : NEG_INF;
        float sv = act ? cloadf(&stats_s[b * 64 + lane]) : 0.f;
        int   ix = act ? cloadi(&stats_i[b * 64 + lane]) : 0x7fffffff;
        float mg = m; int ig = ix;
#pragma unroll
        for (int msk = 1; msk < 64; msk <<= 1) {
          float om = __shfl_xor(mg, msk, 64);
          int oi = __shfl_xor(ig, msk, 64);
          if (om > mg || (om == mg && oi < ig)) { mg = om; ig = oi; }
        }
        float S = wsum64(sv * expf(m - mg));
        if (lane == 0) { cstoref(&mS_g[b * 2], mg); cstoref(&mS_g[b * 2 + 1], S); }
        postflag(&R[t], lane);
        if (t < 63) {
          float y = emb[ig * 64 + lane] + peg[t * 64 + lane];
          Yg[t * 64 + lane] = y;
          Qg[t * 64 + lane] = proj64(y, sa_W, sa_b, lane);
          K1[t * 64 + lane] = proj64(y, sa_W + 4096, sa_b + 64, lane);
          V1[t * 64 + lane] = proj64(y, sa_W + 2 * 4096, sa_b + 128, lane);
        }
      }
    }
  } else {
    // =================== vocab block: fixed 898-column slice ===================
    const int jb = bid - NTB;
    const int vbase = jb * CHUNK;
    const int v = vbase + tid;
    const bool valid = (tid < CHUNK) && (v < Vc);
    float* ftile = lds;                 // (512)
    float* sm = lds + 512;              // (16,8)
    int*   si = (int*)(lds + 640);      // (16,8)
    float* ssm = lds + 768;             // (16,8)
    float* bmx = lds + 896;             // (8)
    int*   bix = (int*)(lds + 904);     // (8)
    float* msl = lds + 920;             // (16)
    float sb = valid ? soft_b[v] : 0.f;

    for (int t = 1; t <= 63; ++t) {
      if (tid == 0) spin_until(&F[t], NTB);
      __syncthreads();
      if (tid < 512) ftile[tid] = cloadf(&tokf_g[tid]);
      __syncthreads();
      float lg[8];
#pragma unroll
      for (int b = 0; b < 8; ++b) lg[b] = valid ? sb : NEG_INF;
      if (valid) {
        for (int e = 0; e < 64; ++e) {
          float wc = soft_W[e * Vc + v];
#pragma unroll
          for (int b = 0; b < 8; ++b) lg[b] = fmaf(ftile[b * 64 + e], wc, lg[b]);
        }
      }
      // block max/argmax per batch
#pragma unroll
      for (int b = 0; b < 8; ++b) {
        float m = lg[b]; int ix = valid ? v : 0x7fffffff;
#pragma unroll
        for (int msk = 1; msk < 64; msk <<= 1) {
          float om = __shfl_xor(m, msk, 64);
          int oi = __shfl_xor(ix, msk, 64);
          if (om > m || (om == m && oi < ix)) { m = om; ix = oi; }
        }
        if (lane == 0) { sm[wvid * 8 + b] = m; si[wvid * 8 + b] = ix; }
      }
      __syncthreads();
      if (tid < 8) {
        float m = NEG_INF; int ix = 0x7fffffff;
        for (int w = 0; w < 16; ++w) {
          float om = sm[w * 8 + tid]; int oi = si[w * 8 + tid];
          if (om > m || (om == m && oi < ix)) { m = om; ix = oi; }
        }
        bmx[tid] = m; bix[tid] = ix;
      }
      __syncthreads();
#pragma unroll
      for (int b = 0; b < 8; ++b) {
        float c = valid ? expf(lg[b] - bmx[b]) : 0.f;
        float s = wsum64(c);
        if (lane == 0) ssm[wvid * 8 + b] = s;
      }
      __syncthreads();
      if (tid < 8) {
        float s = 0.f;
        for (int w = 0; w < 16; ++w) s += ssm[w * 8 + tid];
        cstoref(&stats_m[tid * 64 + jb], bmx[tid]);
        cstoref(&stats_s[tid * 64 + jb], s);
        cstorei(&stats_i[tid * 64 + jb], bix[tid]);
      }
      if (wvid == 0) postflag(&C3[t], tid);
      // ---- wait global m,S; write probs (overlaps next transformer step) ----
      if (tid == 0) spin_until(&R[t], NTB);
      __syncthreads();
      if (tid < 16) msl[tid] = cloadf(&mS_g[tid]);
      __syncthreads();
      if (valid) {
        long base = (long)(t - 1) * Vc + v;
#pragma unroll
        for (int b = 0; b < 8; ++b)
          dout[(long)b * 63 * Vc + base] = expf(lg[b] - msl[2 * b]) / msl[2 * b + 1];
      }
      __syncthreads();  // protect ftile/lds reuse next iteration
    }
  }
}

extern "C" void kernel_launch(void* const* d_in, const int* in_sizes, int n_in,
                              void* d_out, int out_size, void* d_ws, size_t ws_size,
                              hipStream_t stream) {
  (void)in_sizes; (void)n_in; (void)out_size; (void)ws_size;
  hipMemsetAsync(d_ws, 0, 4096, stream);  // zero flag arrays
  gen_kernel<<<dim3(NTB + NP3), dim3(1024), 0, stream>>>(
      (const float*)d_in[0], (const float*)d_in[1], (const float*)d_in[2],
      (const float*)d_in[3], (const float*)d_in[4], (const float*)d_in[5],
      (const float*)d_in[6], (const float*)d_in[7], (const float*)d_in[8],
      (const float*)d_in[9], (const float*)d_in[10], (const float*)d_in[11],
      (const float*)d_in[12], (const float*)d_in[13], (const float*)d_in[14],
      (const float*)d_in[15], (const int*)d_in[16],
      (float*)d_out, (float*)d_ws);
}

// Round 3
// 24481.569 us; speedup vs baseline: 2.9768x; 1.5964x over previous
//
#include <hip/hip_runtime.h>
#include <math.h>

#define Vc 50257
#define NEG_INF (-__builtin_inff())
#define CHUNK 898   // vocab columns per vocab block (56*898 >= 50257)
#define NVB 56      // vocab blocks
#define NRB 128     // row blocks: 16 per batch * 8 batches
#define NB  8       // batches

// ---------------- wave-level helpers ----------------

__device__ __forceinline__ float wsum64(float v) {
#pragma unroll
  for (int m = 32; m >= 1; m >>= 1) v += __shfl_xor(v, m, 64);
  return v;
}

__device__ __forceinline__ float red8(float v) {
  v += __shfl_xor(v, 1, 64);
  v += __shfl_xor(v, 2, 64);
  v += __shfl_xor(v, 4, 64);
  return v;
}

// out[lane] = bias[lane] + sum_e x[e]*W[e*64+lane]; x broadcast via LDS float4 reads
__device__ __forceinline__ float proj_lds(float xv, float* xb,
                                          const float* __restrict__ W,
                                          const float* __restrict__ bias, int lane) {
  xb[lane] = xv;
  asm volatile("s_waitcnt lgkmcnt(0)" ::: "memory");
  float acc = bias[lane];
  const float4* x4 = (const float4*)xb;
#pragma unroll
  for (int i = 0; i < 16; ++i) {
    float4 xc = x4[i];
    acc = fmaf(xc.x, W[(4 * i + 0) * 64 + lane], acc);
    acc = fmaf(xc.y, W[(4 * i + 1) * 64 + lane], acc);
    acc = fmaf(xc.z, W[(4 * i + 2) * 64 + lane], acc);
    acc = fmaf(xc.w, W[(4 * i + 3) * 64 + lane], acc);
  }
  asm volatile("" ::: "memory");
  return acc;
}

__device__ __forceinline__ float ln64(float xv, const float* __restrict__ g,
                                      const float* __restrict__ b, int lane) {
  float mean = wsum64(xv) * 0.015625f;
  float d = xv - mean;
  float var = wsum64(d * d) * 0.015625f;
  float r = 1.0f / sqrtf(var + 1e-5f);
  return d * r * g[lane] + b[lane];
}

// ------------- coherent cross-block access: relaxed agent atomics (no cache wipes) -------------

__device__ __forceinline__ float cloadf(const float* p) {
  return __hip_atomic_load(p, __ATOMIC_RELAXED, __HIP_MEMORY_SCOPE_AGENT);
}
__device__ __forceinline__ int cloadi(const int* p) {
  return __hip_atomic_load(p, __ATOMIC_RELAXED, __HIP_MEMORY_SCOPE_AGENT);
}
__device__ __forceinline__ void cstoref(float* p, float v) {
  __hip_atomic_store(p, v, __ATOMIC_RELAXED, __HIP_MEMORY_SCOPE_AGENT);
}
__device__ __forceinline__ void cstorei(int* p, int v) {
  __hip_atomic_store(p, v, __ATOMIC_RELAXED, __HIP_MEMORY_SCOPE_AGENT);
}
__device__ __forceinline__ void spin_until(int* f, int target) {
  while (__hip_atomic_load(f, __ATOMIC_RELAXED, __HIP_MEMORY_SCOPE_AGENT) < target)
    __builtin_amdgcn_s_sleep(4);
  __builtin_amdgcn_s_waitcnt(0);
}
__device__ __forceinline__ void postflag(int* f, int lane) {
  __builtin_amdgcn_s_waitcnt(0);
  if (lane == 0) __hip_atomic_fetch_add(f, 1, __ATOMIC_RELAXED, __HIP_MEMORY_SCOPE_AGENT);
}

struct LayerR {
  const float *saW3, *sab3, *caW0, *cab0, *caW3, *cab3,
              *ffW1, *ffb1, *ffW2, *ffb2, *g0, *be0, *g1, *be1, *g2, *be2;
  float cs1_r, cs2_r, cab1_r, cab2_r;
};

// One wave, one row. K/V in LDS; wv in LDS (float4 broadcast); xb = this wave's LDS scratch.
__device__ float transformer_row(int lane, int t, float x, float q,
                                 const float* Kb, const float* Vb,
                                 const float* wv, float* xb, const LayerR& P) {
  const float ISQ8 = 0.35355339059327373f;  // 1/sqrt(8)
  float mh = NEG_INF;
  for (int k = 0; k < t; ++k) {
    float s = red8(q * Kb[k * 64 + lane]) * ISQ8;
    mh = fmaxf(mh, s);
  }
  float l = 0.f, o = 0.f;
  for (int k = 0; k < t; ++k) {
    float s = red8(q * Kb[k * 64 + lane]) * ISQ8;
    float pw = expf(s - mh);
    l += pw;
    o = fmaf(pw, Vb[k * 64 + lane], o);
  }
  float attn = o / l;
  float y1 = ln64(x + proj_lds(attn, xb, P.saW3, P.sab3, lane), P.g0, P.be0, lane);
  float qc = proj_lds(y1, xb, P.caW0, P.cab0, lane);
  float pa = red8(qc * P.cs1_r);
  float pc = red8(qc * P.cab1_r);
  const float4* wv4 = (const float4*)wv;
  float mc = NEG_INF;
#pragma unroll
  for (int i = 0; i < 16; ++i) {
    float4 wq = wv4[i];
    int k = 4 * i;
    if (k + 0 < t) mc = fmaxf(mc, fmaf(pa, wq.x, pc));
    if (k + 1 < t) mc = fmaxf(mc, fmaf(pa, wq.y, pc));
    if (k + 2 < t) mc = fmaxf(mc, fmaf(pa, wq.z, pc));
    if (k + 3 < t) mc = fmaxf(mc, fmaf(pa, wq.w, pc));
  }
  float lc = 0.f, z = 0.f;
#pragma unroll
  for (int i = 0; i < 16; ++i) {
    float4 wq = wv4[i];
    int k = 4 * i;
    float wk[4] = {wq.x, wq.y, wq.z, wq.w};
#pragma unroll
    for (int j = 0; j < 4; ++j) {
      if (k + j < t) {
        float raw = fmaf(pa, wk[j], pc);
        float pw = expf((raw - mc) * ISQ8);
        lc += pw;
        z = fmaf(pw, wk[j], z);
      }
    }
  }
  float oc = fmaf(z / lc, P.cs2_r, P.cab2_r);
  float y2 = ln64(y1 + proj_lds(oc, xb, P.caW3, P.cab3, lane), P.g1, P.be1, lane);
  float f = fmaxf(proj_lds(y2, xb, P.ffW1, P.ffb1, lane), 0.f);
  float y3 = ln64(y2 + proj_lds(f, xb, P.ffW2, P.ffb2, lane), P.g2, P.be2, lane);
  return y3;
}

__device__ __forceinline__ void build_layer(LayerR& L, int n, int lane,
    const float* sa_W, const float* sa_b, const float* ca_W, const float* ca_b,
    const float* ff_W1, const float* ff_b1, const float* ff_W2, const float* ff_b2,
    const float* ln_g, const float* ln_b) {
  L.saW3 = sa_W + (n * 4 + 3) * 4096; L.sab3 = sa_b + (n * 4 + 3) * 64;
  L.caW0 = ca_W + (n * 4 + 0) * 4096; L.cab0 = ca_b + (n * 4 + 0) * 64;
  L.caW3 = ca_W + (n * 4 + 3) * 4096; L.cab3 = ca_b + (n * 4 + 3) * 64;
  L.ffW1 = ff_W1 + n * 4096;          L.ffb1 = ff_b1 + n * 64;
  L.ffW2 = ff_W2 + n * 4096;          L.ffb2 = ff_b2 + n * 64;
  L.g0 = ln_g + (n * 3 + 0) * 64;     L.be0 = ln_b + (n * 3 + 0) * 64;
  L.g1 = ln_g + (n * 3 + 1) * 64;     L.be1 = ln_b + (n * 3 + 1) * 64;
  L.g2 = ln_g + (n * 3 + 2) * 64;     L.be2 = ln_b + (n * 3 + 2) * 64;
  L.cab1_r = ca_b[(n * 4 + 1) * 64 + lane];
  L.cab2_r = ca_b[(n * 4 + 2) * 64 + lane];
  float c1 = 0.f, c2 = 0.f;
  for (int e = 0; e < 64; ++e) {
    c1 += ca_W[(n * 4 + 1) * 4096 + e * 64 + lane];
    c2 += ca_W[(n * 4 + 2) * 4096 + e * 64 + lane];
  }
  L.cs1_r = c1; L.cs2_r = c2;
}

__global__ __launch_bounds__(1024) void gen_kernel(
    const float* __restrict__ noise, const float* __restrict__ lin_W,
    const float* __restrict__ lin_b, const float* __restrict__ sa_W,
    const float* __restrict__ sa_b, const float* __restrict__ ca_W,
    const float* __restrict__ ca_b, const float* __restrict__ ff_W1,
    const float* __restrict__ ff_b1, const float* __restrict__ ff_W2,
    const float* __restrict__ ff_b2, const float* __restrict__ ln_g,
    const float* __restrict__ ln_b, const float* __restrict__ emb,
    const float* __restrict__ soft_W, const float* __restrict__ soft_b,
    const int* __restrict__ start_id, float* __restrict__ dout,
    float* __restrict__ wsf) {
  const int tid = threadIdx.x, lane = tid & 63, wvid = tid >> 6;
  const int bid = blockIdx.x;

  // ---- workspace: flags in first 8 KB (memset-zeroed), data after ----
  int* wsi = (int*)wsf;
  int* KVF = wsi;            // [8][64]  new-row published     (target 1)
  int* RBc = wsi + 512;      // [8][64]  row-block arrivals    (target 16)
  int* Ff  = wsi + 1024;     // [64]     tok_feat ready        (target 8)
  int* C3f = wsi + 1088;     // [64]     vocab stats ready     (target 56)
  int* Rf  = wsi + 1152;     // [64]     m/S ready             (target 8)
  float* tokf_g  = wsf + 2048;          // (8,64)
  float* stats_m = wsf + 2560;          // (8,64) use 56
  float* stats_s = wsf + 3072;
  int*   stats_i = (int*)(wsf + 3584);
  float* mS_g    = wsf + 4096;          // (8,2)
  float* x2g     = wsf + 4160;          // (8,64)
  float* Yg  = wsf + 8192;              // (8, 4096) stride per batch
  float* Qg  = Yg  + 8 * 4096;
  float* K1g = Qg  + 8 * 4096;
  float* V1g = K1g + 8 * 4096;
  float* K2g = V1g + 8 * 4096;
  float* V2g = K2g + 8 * 4096;          // total ws ~820 KB

  __shared__ float lds[16448];          // 65792 B
  float* K1   = lds;                    // (63,64)
  float* V1   = lds + 4032;
  float* K2   = lds + 8064;             // leader only
  float* V2   = lds + 12096;
  float* wvl  = lds + 16128;            // (64)
  float* xbuf = lds + 16192;            // 4 waves * 64

  if (bid < NRB) {
    // =================== row block: 16 per batch, 1 row per wave ===================
    const int b = bid & 7, rb = bid >> 3;
    const bool leader = (rb == 0);
    const bool rowwave = (wvid < 4);
    const int w = rb * 4 + wvid;        // row owned by this wave (if rowwave)
    float* myxb = xbuf + (wvid & 3) * 64;

    LayerR L0, L1;
    if (rowwave) {
      build_layer(L0, 0, lane, sa_W, sa_b, ca_W, ca_b, ff_W1, ff_b1, ff_W2, ff_b2, ln_g, ln_b);
      float nz = noise[b * 64 + lane];
      float t1v = proj_lds(nz, myxb, lin_W, lin_b, lane);
      float wv_r = proj_lds(t1v, myxb, lin_W + 4096, lin_b + 64, lane);
      if (wvid == 0) wvl[lane] = wv_r;
    }
    if (leader && wvid == 0) {
      build_layer(L1, 1, lane, sa_W, sa_b, ca_W, ca_b, ff_W1, ff_b1, ff_W2, ff_b2, ln_g, ln_b);
      // seed row 0 (pe[0]: sin->0, cos->1)
      float y0 = emb[start_id[0] * 64 + lane] + ((lane & 1) ? 1.0f : 0.0f);
      float q0 = proj_lds(y0, myxb, sa_W, sa_b, lane);
      float k0 = proj_lds(y0, myxb, sa_W + 4096, sa_b + 64, lane);
      float v0 = proj_lds(y0, myxb, sa_W + 2 * 4096, sa_b + 128, lane);
      cstoref(Yg + b * 4096 + lane, y0);
      cstoref(Qg + b * 4096 + lane, q0);
      cstoref(K1g + b * 4096 + lane, k0);
      cstoref(V1g + b * 4096 + lane, v0);
      postflag(&KVF[b * 64 + 1], lane);
    }
    __syncthreads();

    float x_r = 0.f, q_r = 0.f;
    bool have = false;
    for (int t = 1; t <= 63; ++t) {
      if (tid == 0) spin_until(&KVF[b * 64 + t], 1);
      __syncthreads();
      if (wvid == 0) {  // append new K1/V1 row (t-1) to LDS copy
        K1[(t - 1) * 64 + lane] = cloadf(K1g + b * 4096 + (t - 1) * 64 + lane);
        V1[(t - 1) * 64 + lane] = cloadf(V1g + b * 4096 + (t - 1) * 64 + lane);
      }
      __syncthreads();
      if (rowwave && w < t) {
        if (!have) {
          x_r = cloadf(Yg + b * 4096 + w * 64 + lane);
          q_r = cloadf(Qg + b * 4096 + w * 64 + lane);
          have = true;
        }
        float out = transformer_row(lane, t, x_r, q_r, K1, V1, wvl, myxb, L0);
        float k2 = proj_lds(out, myxb, sa_W + 5 * 4096, sa_b + 5 * 64, lane);
        float v2 = proj_lds(out, myxb, sa_W + 6 * 4096, sa_b + 6 * 64, lane);
        cstoref(K2g + b * 4096 + w * 64 + lane, k2);
        cstoref(V2g + b * 4096 + w * 64 + lane, v2);
        if (w == t - 1) cstoref(x2g + b * 64 + lane, out);
        __builtin_amdgcn_s_waitcnt(0);  // drain my agent stores
      }
      __syncthreads();
      if (tid == 0)
        __hip_atomic_fetch_add(&RBc[b * 64 + t], 1, __ATOMIC_RELAXED, __HIP_MEMORY_SCOPE_AGENT);

      if (leader && wvid == 0) {
        // ---- P2: layer-2 row t-1 ----
        spin_until(&RBc[b * 64 + t], 16);
        for (int k = 0; k < t; ++k) {
          K2[k * 64 + lane] = cloadf(K2g + b * 4096 + k * 64 + lane);
          V2[k * 64 + lane] = cloadf(V2g + b * 4096 + k * 64 + lane);
        }
        float x2 = cloadf(x2g + b * 64 + lane);
        float q2 = proj_lds(x2, myxb, sa_W + 4 * 4096, sa_b + 4 * 64, lane);
        float tf = transformer_row(lane, t, x2, q2, K2, V2, wvl, myxb, L1);
        cstoref(tokf_g + b * 64 + lane, tf);
        postflag(&Ff[t], lane);
        // pe row t (off critical path: computed while vocab works)
        float pev = 0.f;
        if (t < 63) {
          double ang = (double)t / pow(10000.0, (double)(lane & 62) / 64.0);
          pev = (lane & 1) ? (float)cos(ang) : (float)sin(ang);
        }
        // ---- reduce vocab stats ----
        spin_until(&C3f[t], NVB);
        bool act = lane < NVB;
        float m = act ? cloadf(&stats_m[b * 64 + lane]) : NEG_INF;
        float sv = act ? cloadf(&stats_s[b * 64 + lane]) : 0.f;
        int ix = act ? cloadi(&stats_i[b * 64 + lane]) : 0x7fffffff;
        float mg = m; int ig = ix;
#pragma unroll
        for (int msk = 1; msk < 64; msk <<= 1) {
          float om = __shfl_xor(mg, msk, 64);
          int oi = __shfl_xor(ig, msk, 64);
          if (om > mg || (om == mg && oi < ig)) { mg = om; ig = oi; }
        }
        float S = wsum64(act ? sv * expf(m - mg) : 0.f);
        if (lane == 0) { cstoref(&mS_g[b * 2], mg); cstoref(&mS_g[b * 2 + 1], S); }
        postflag(&Rf[t], lane);
        // ---- P4: new row t ----
        if (t < 63) {
          float y = emb[ig * 64 + lane] + pev;
          float qn = proj_lds(y, myxb, sa_W, sa_b, lane);
          float kn = proj_lds(y, myxb, sa_W + 4096, sa_b + 64, lane);
          float vn = proj_lds(y, myxb, sa_W + 2 * 4096, sa_b + 128, lane);
          cstoref(Yg + b * 4096 + t * 64 + lane, y);
          cstoref(Qg + b * 4096 + t * 64 + lane, qn);
          cstoref(K1g + b * 4096 + t * 64 + lane, kn);
          cstoref(V1g + b * 4096 + t * 64 + lane, vn);
          postflag(&KVF[b * 64 + t + 1], lane);
        }
      }
    }
  } else {
    // =================== vocab block: fixed 898-column slice ===================
    const int jb = bid - NRB;
    const int v = jb * CHUNK + tid;
    const bool valid = (tid < CHUNK) && (v < Vc);
    float* ftile = lds;                 // (512)
    float* sm = lds + 512;              // (16,8)
    int*   si = (int*)(lds + 640);
    float* ssm = lds + 768;
    float* bmx = lds + 896;
    int*   bix = (int*)(lds + 904);
    float* msl = lds + 920;             // (16)
    float sb = valid ? soft_b[v] : 0.f;

    for (int t = 1; t <= 63; ++t) {
      if (tid == 0) spin_until(&Ff[t], NB);
      __syncthreads();
      if (tid < 512) ftile[tid] = cloadf(&tokf_g[tid]);
      __syncthreads();
      float lg[8];
#pragma unroll
      for (int b = 0; b < 8; ++b) lg[b] = valid ? sb : NEG_INF;
      if (valid) {
        for (int e = 0; e < 64; ++e) {
          float wc = soft_W[e * Vc + v];
#pragma unroll
          for (int b = 0; b < 8; ++b) lg[b] = fmaf(ftile[b * 64 + e], wc, lg[b]);
        }
      }
#pragma unroll
      for (int b = 0; b < 8; ++b) {
        float m = lg[b]; int ix = valid ? v : 0x7fffffff;
#pragma unroll
        for (int msk = 1; msk < 64; msk <<= 1) {
          float om = __shfl_xor(m, msk, 64);
          int oi = __shfl_xor(ix, msk, 64);
          if (om > m || (om == m && oi < ix)) { m = om; ix = oi; }
        }
        if (lane == 0) { sm[wvid * 8 + b] = m; si[wvid * 8 + b] = ix; }
      }
      __syncthreads();
      if (tid < 8) {
        float m = NEG_INF; int ix = 0x7fffffff;
        for (int wv = 0; wv < 16; ++wv) {
          float om = sm[wv * 8 + tid]; int oi = si[wv * 8 + tid];
          if (om > m || (om == m && oi < ix)) { m = om; ix = oi; }
        }
        bmx[tid] = m; bix[tid] = ix;
      }
      __syncthreads();
#pragma unroll
      for (int b = 0; b < 8; ++b) {
        float c = valid ? expf(lg[b] - bmx[b]) : 0.f;
        float s = wsum64(c);
        if (lane == 0) ssm[wvid * 8 + b] = s;
      }
      __syncthreads();
      if (tid < 8) {
        float s = 0.f;
        for (int wv = 0; wv < 16; ++wv) s += ssm[wv * 8 + tid];
        cstoref(&stats_m[tid * 64 + jb], bmx[tid]);
        cstoref(&stats_s[tid * 64 + jb], s);
        cstorei(&stats_i[tid * 64 + jb], bix[tid]);
      }
      if (wvid == 0) postflag(&C3f[t], tid);
      if (tid == 0) spin_until(&Rf[t], NB);
      __syncthreads();
      if (tid < 16) msl[tid] = cloadf(&mS_g[tid]);
      __syncthreads();
      if (valid) {
        long base = (long)(t - 1) * Vc + v;
#pragma unroll
        for (int b = 0; b < 8; ++b)
          dout[(long)b * 63 * Vc + base] = expf(lg[b] - msl[2 * b]) / msl[2 * b + 1];
      }
      __syncthreads();
    }
  }
}

extern "C" void kernel_launch(void* const* d_in, const int* in_sizes, int n_in,
                              void* d_out, int out_size, void* d_ws, size_t ws_size,
                              hipStream_t stream) {
  (void)in_sizes; (void)n_in; (void)out_size; (void)ws_size;
  hipMemsetAsync(d_ws, 0, 8192, stream);  // zero all flag arrays
  gen_kernel<<<dim3(NRB + NVB), dim3(1024), 0, stream>>>(
      (const float*)d_in[0], (const float*)d_in[1], (const float*)d_in[2],
      (const float*)d_in[3], (const float*)d_in[4], (const float*)d_in[5],
      (const float*)d_in[6], (const float*)d_in[7], (const float*)d_in[8],
      (const float*)d_in[9], (const float*)d_in[10], (const float*)d_in[11],
      (const float*)d_in[12], (const float*)d_in[13], (const float*)d_in[14],
      (const float*)d_in[15], (const int*)d_in[16],
      (float*)d_out, (float*)d_ws);
}